// Round 2
// baseline (1276.235 us; speedup 1.0000x reference)
//
#include <hip/hip_runtime.h>

// AttentionWindow: out = repr + relu(softmax_masked((repr@W)@repr^T) @ repr)
// BATCH=8, SEQ=2048, HIDDEN=1024, window half-width 64 (|i-j|>64 masked).
// Fully fused single kernel, no workspace. Dual-dtype (bf16 / fp32) with
// per-block uniform data-driven detection; both template instantiations are
// launched, exactly one does the work.

#define SEQL 2048
#define HID  1024
#define NB   8
#define QT   32     // queries per block
#define KT   160    // candidate keys: [q0-64, q0+95]
#define DCO  128    // d-chunk for Qc GEMM (Qc[32][128] in registers)
#define EC   32     // e-chunk staged per inner GEMM step
#define DS   32     // d-slice width for Ks staging / S-FMA / phase B
#define RP   36     // Rs pitch (floats)
#define WP   132    // Ws pitch
#define QP   132    // Qcs pitch
#define KP   36     // Ks pitch
#define SP   161    // Sc pitch

// LDS arena (floats). Phase-disjoint aliasing:
//   [0,1152)        Rs   (Qc-GEMM inner)
//   [1152,5376)     Ws   (Qc-GEMM inner)
//   [0,5760)        Ks   (S-FMA slices, phase B)
//   [5760,9984)     Qcs  (S-FMA slices)
//   [5760,10912)    Sc   (softmax, phase B)
#define RS_OFF  0
#define WS_OFF  1152
#define KS_OFF  0
#define QCS_OFF 5760
#define SC_OFF  5760
#define SMEM_F  10912   // 43648 bytes

__device__ __forceinline__ float bfu(unsigned int lo16) {
  union { unsigned int i; float f; } v; v.i = lo16 << 16; return v.f;
}
__device__ __forceinline__ unsigned short f2bf(float f) {
  union { float f; unsigned int i; } v; v.f = f;
  unsigned int r = v.i + 0x7FFFu + ((v.i >> 16) & 1u);   // RNE
  return (unsigned short)(r >> 16);
}

// Uniform (thread-invariant) dtype sniff: read repr[0..255] as u16. For bf16
// data nearly all have plausible N(0,1) exponents; for fp32 data the even
// halves are random mantissa bits (~10% plausible) -> count ~140 vs ~256.
__device__ bool data_is_bf16(const unsigned short* u) {
  int cnt = 0;
  for (int i = 0; i < 256; i++) {
    int e = (u[i] >> 7) & 0xFF;
    if (e >= 107 && e <= 131) cnt++;   // |x| in ~[2^-20, 2^5)
  }
  return cnt >= 230;
}

template<bool BF16>
__device__ __forceinline__ float4 ld4(const void* p, size_t idx) {
  if (BF16) {
    uint2 u = *(const uint2*)((const unsigned short*)p + idx);
    float4 r;
    r.x = bfu(u.x & 0xFFFFu); r.y = bfu(u.x >> 16);
    r.z = bfu(u.y & 0xFFFFu); r.w = bfu(u.y >> 16);
    return r;
  } else {
    return *(const float4*)((const float*)p + idx);
  }
}

template<bool BF16>
__device__ __forceinline__ void st4(void* p, size_t idx, float4 v) {
  if (BF16) {
    ushort4 o;
    o.x = f2bf(v.x); o.y = f2bf(v.y); o.z = f2bf(v.z); o.w = f2bf(v.w);
    *(ushort4*)((unsigned short*)p + idx) = o;
  } else {
    *(float4*)((float*)p + idx) = v;
  }
}

__device__ __forceinline__ void fma4(float4& q, float a, const float4& w) {
  q.x += a * w.x; q.y += a * w.y; q.z += a * w.z; q.w += a * w.w;
}

template<bool BF16>
__global__ void __launch_bounds__(256) attn_fused(
    const void* __restrict__ reprv, const void* __restrict__ Wv,
    void* __restrict__ outv) {
  // Uniform early-out before any __syncthreads (no deadlock risk).
  if (data_is_bf16((const unsigned short*)reprv) != BF16) return;

  __shared__ float smem[SMEM_F];
  const int tid = threadIdx.x;
  const int b = blockIdx.y;
  const int q0 = blockIdx.x * QT;
  const size_t baseR = (size_t)b * SEQL * HID;

  // Shared thread decomposition: ty=tr in 0..7, tx=tc in 0..31.
  const int tx = tid & 31, ty = tid >> 5;

  float acc[4][5];   // S[q=ty+8i][k=tx+32j]
#pragma unroll
  for (int i = 0; i < 4; i++)
#pragma unroll
    for (int j = 0; j < 5; j++) acc[i][j] = 0.f;

  // ---------------- Phase A: scores ----------------
  for (int d0 = 0; d0 < HID; d0 += DCO) {
    // Qc[32][128] in registers: rows ty+8i, cols 4*tx..4*tx+3
    float4 qc[4];
#pragma unroll
    for (int i = 0; i < 4; i++) qc[i] = make_float4(0.f, 0.f, 0.f, 0.f);

    for (int e0 = 0; e0 < HID; e0 += EC) {
      {  // stage Rs[32][32]: repr[q0+row][e0+4cg..]
        int row = tid >> 3, cg = tid & 7;
        float4 v = ld4<BF16>(reprv, baseR + (size_t)(q0 + row) * HID + e0 + 4 * cg);
        *(float4*)&smem[RS_OFF + row * RP + 4 * cg] = v;
      }
#pragma unroll
      for (int i2 = 0; i2 < 4; i2++) {  // stage Ws[32][128]: W[e0+row][d0+4cg..]
        int f = i2 * 256 + tid;
        int row = f >> 5, cg = f & 31;
        float4 v = ld4<BF16>(Wv, (size_t)(e0 + row) * HID + d0 + 4 * cg);
        *(float4*)&smem[WS_OFF + row * WP + 4 * cg] = v;
      }
      __syncthreads();
#pragma unroll
      for (int ee = 0; ee < EC; ee += 4) {
        float4 rv[4];
#pragma unroll
        for (int i = 0; i < 4; i++)
          rv[i] = *(const float4*)&smem[RS_OFF + (ty + 8 * i) * RP + ee];
        {
          float4 wv = *(const float4*)&smem[WS_OFF + (ee + 0) * WP + 4 * tx];
          fma4(qc[0], rv[0].x, wv); fma4(qc[1], rv[1].x, wv);
          fma4(qc[2], rv[2].x, wv); fma4(qc[3], rv[3].x, wv);
        }
        {
          float4 wv = *(const float4*)&smem[WS_OFF + (ee + 1) * WP + 4 * tx];
          fma4(qc[0], rv[0].y, wv); fma4(qc[1], rv[1].y, wv);
          fma4(qc[2], rv[2].y, wv); fma4(qc[3], rv[3].y, wv);
        }
        {
          float4 wv = *(const float4*)&smem[WS_OFF + (ee + 2) * WP + 4 * tx];
          fma4(qc[0], rv[0].z, wv); fma4(qc[1], rv[1].z, wv);
          fma4(qc[2], rv[2].z, wv); fma4(qc[3], rv[3].z, wv);
        }
        {
          float4 wv = *(const float4*)&smem[WS_OFF + (ee + 3) * WP + 4 * tx];
          fma4(qc[0], rv[0].w, wv); fma4(qc[1], rv[1].w, wv);
          fma4(qc[2], rv[2].w, wv); fma4(qc[3], rv[3].w, wv);
        }
      }
      __syncthreads();
    }

    // Qc registers -> Qcs LDS (region disjoint from Ks)
#pragma unroll
    for (int i = 0; i < 4; i++)
      *(float4*)&smem[QCS_OFF + (ty + 8 * i) * QP + 4 * tx] = qc[i];

    // S-FMA over 32-wide slices of this d-chunk
    for (int s = 0; s < DCO; s += DS) {
#pragma unroll
      for (int i2 = 0; i2 < 5; i2++) {  // stage Ks[160][32]
        int f = i2 * 256 + tid;
        int row = f >> 3, cg = f & 7;
        int kk = q0 - 64 + row;
        kk = kk < 0 ? 0 : (kk > SEQL - 1 ? SEQL - 1 : kk);  // clamped rows masked later
        float4 v = ld4<BF16>(reprv, baseR + (size_t)kk * HID + d0 + s + 4 * cg);
        *(float4*)&smem[KS_OFF + row * KP + 4 * cg] = v;
      }
      __syncthreads();  // also covers the Qcs write (first slice)
#pragma unroll
      for (int dd = 0; dd < DS; dd += 4) {
        float4 qv[4];
#pragma unroll
        for (int i = 0; i < 4; i++)
          qv[i] = *(const float4*)&smem[QCS_OFF + (ty + 8 * i) * QP + s + dd];
#pragma unroll
        for (int j = 0; j < 5; j++) {
          float4 kv = *(const float4*)&smem[KS_OFF + (tx + 32 * j) * KP + dd];
#pragma unroll
          for (int i = 0; i < 4; i++)
            acc[i][j] += qv[i].x * kv.x + qv[i].y * kv.y + qv[i].z * kv.z + qv[i].w * kv.w;
        }
      }
      __syncthreads();
    }
  }

  // scores -> Sc (Qcs dead)
#pragma unroll
  for (int i = 0; i < 4; i++)
#pragma unroll
    for (int j = 0; j < 5; j++)
      smem[SC_OFF + (ty + 8 * i) * SP + tx + 32 * j] = acc[i][j];
  __syncthreads();

  // ---------------- masked softmax: 8 lanes per query row ----------------
  {
    const int row = tid >> 3, l8 = tid & 7;
    int clo = row;          { int t = 64 - q0;            if (t > clo) clo = t; }
    int chi = row + 128;    { int t = SEQL - 1 + 64 - q0; if (t < chi) chi = t; }
    float m = -1e30f;
    for (int c = l8; c < KT; c += 8)
      if (c >= clo && c <= chi) m = fmaxf(m, smem[SC_OFF + row * SP + c]);
    m = fmaxf(m, __shfl_xor(m, 1));
    m = fmaxf(m, __shfl_xor(m, 2));
    m = fmaxf(m, __shfl_xor(m, 4));
    float ssum = 0.f;
    for (int c = l8; c < KT; c += 8) {
      float e = (c >= clo && c <= chi) ? __expf(smem[SC_OFF + row * SP + c] - m) : 0.f;
      smem[SC_OFF + row * SP + c] = e;
      ssum += e;
    }
    ssum += __shfl_xor(ssum, 1);
    ssum += __shfl_xor(ssum, 2);
    ssum += __shfl_xor(ssum, 4);
    float rinv = 1.f / ssum;
    for (int c = l8; c < KT; c += 8) smem[SC_OFF + row * SP + c] *= rinv;
  }
  __syncthreads();

  // ---------------- Phase B: ra = P @ K, out = repr + relu(ra) -----------
  const int rr = tid >> 3, dq = tid & 7;
  for (int d0 = 0; d0 < HID; d0 += DS) {
#pragma unroll
    for (int i2 = 0; i2 < 5; i2++) {  // stage Ks[160][32] at d0
      int f = i2 * 256 + tid;
      int row = f >> 3, cg = f & 7;
      int kk = q0 - 64 + row;
      kk = kk < 0 ? 0 : (kk > SEQL - 1 ? SEQL - 1 : kk);
      float4 v = ld4<BF16>(reprv, baseR + (size_t)kk * HID + d0 + 4 * cg);
      *(float4*)&smem[KS_OFF + row * KP + 4 * cg] = v;
    }
    __syncthreads();
    float4 o = make_float4(0.f, 0.f, 0.f, 0.f);
#pragma unroll 4
    for (int c = 0; c < KT; c++) {
      float4 kv = *(const float4*)&smem[KS_OFF + c * KP + 4 * dq];
      float p = smem[SC_OFF + rr * SP + c];
      o.x += p * kv.x; o.y += p * kv.y; o.z += p * kv.z; o.w += p * kv.w;
    }
    size_t goff = baseR + (size_t)(q0 + rr) * HID + d0 + 4 * dq;
    float4 rv = ld4<BF16>(reprv, goff);
    float4 ov;
    ov.x = rv.x + fmaxf(o.x, 0.f);
    ov.y = rv.y + fmaxf(o.y, 0.f);
    ov.z = rv.z + fmaxf(o.z, 0.f);
    ov.w = rv.w + fmaxf(o.w, 0.f);
    st4<BF16>(outv, goff, ov);
    __syncthreads();
  }
}

extern "C" void kernel_launch(void* const* d_in, const int* in_sizes, int n_in,
                              void* d_out, int out_size, void* d_ws, size_t ws_size,
                              hipStream_t stream) {
  const void* repr = d_in[0];
  const void* W    = d_in[1];
  dim3 grid(SEQL / QT, NB);   // (64, 8) = 512 blocks
  attn_fused<true ><<<grid, dim3(256), 0, stream>>>(repr, W, d_out);
  attn_fused<false><<<grid, dim3(256), 0, stream>>>(repr, W, d_out);
}